// Round 1
// baseline (587.909 us; speedup 1.0000x reference)
//
#include <hip/hip_runtime.h>

// 3D trilinear warp (SpatialTransformer): out[b,c,z,y,x] =
//   sum over 8 corners of w * src[b,c,zc,yc,xc], zeros padding.
// B=2, C=2, D=H=W=160, fp32.

constexpr int Bv = 2, Cv = 2, Dv = 160, Hv = 160, Wv = 160;
constexpr int V = Dv * Hv * Wv;          // 4,096,000 spatial sites per batch
constexpr int TOTAL = Bv * V;            // 8,192,000 threads

__global__ __launch_bounds__(256) void warp3d_kernel(
    const float* __restrict__ src,   // [B, C, D, H, W]
    const float* __restrict__ flow,  // [B, 3, D, H, W]
    float* __restrict__ out)         // [B, C, D, H, W]
{
    int i = blockIdx.x * blockDim.x + threadIdx.x;
    if (i >= TOTAL) return;

    int b = i / V;
    int s = i - b * V;                 // (z*H + y)*W + x
    int x = s % Wv;
    int t = s / Wv;
    int y = t % Hv;
    int z = t / Hv;

    const float* fb = flow + (size_t)b * 3 * V;
    float pz = (float)z + fb[s];
    float py = (float)y + fb[s + V];
    float px = (float)x + fb[s + 2 * V];

    float z0f = floorf(pz), y0f = floorf(py), x0f = floorf(px);
    float fz = pz - z0f, fy = py - y0f, fx = px - x0f;
    int z0 = (int)z0f, y0 = (int)y0f, x0 = (int)x0f;

    const float* s0 = src + (size_t)b * Cv * V;   // channel 0
    const float* s1 = s0 + V;                      // channel 1

    float acc0 = 0.f, acc1 = 0.f;

    #pragma unroll
    for (int dz = 0; dz < 2; ++dz) {
        int zi = z0 + dz;
        bool vz = (unsigned)zi < (unsigned)Dv;
        float wz = dz ? fz : (1.0f - fz);
        #pragma unroll
        for (int dy = 0; dy < 2; ++dy) {
            int yi = y0 + dy;
            bool vy = (unsigned)yi < (unsigned)Hv;
            float wy = dy ? fy : (1.0f - fy);
            #pragma unroll
            for (int dx = 0; dx < 2; ++dx) {
                int xi = x0 + dx;
                bool vx = (unsigned)xi < (unsigned)Wv;
                float wx = dx ? fx : (1.0f - fx);
                if (vz & vy & vx) {
                    int idx = (zi * Hv + yi) * Wv + xi;
                    float w = wz * wy * wx;
                    acc0 = fmaf(w, s0[idx], acc0);
                    acc1 = fmaf(w, s1[idx], acc1);
                }
            }
        }
    }

    size_t ob = (size_t)b * Cv * V;
    out[ob + s]     = acc0;
    out[ob + V + s] = acc1;
}

extern "C" void kernel_launch(void* const* d_in, const int* in_sizes, int n_in,
                              void* d_out, int out_size, void* d_ws, size_t ws_size,
                              hipStream_t stream) {
    const float* src  = (const float*)d_in[0];
    const float* flow = (const float*)d_in[1];
    float* out = (float*)d_out;

    int block = 256;
    int grid = (TOTAL + block - 1) / block;   // 32000 blocks
    warp3d_kernel<<<grid, block, 0, stream>>>(src, flow, out);
}

// Round 5
// 381.754 us; speedup vs baseline: 1.5400x; 1.5400x over previous
//
#include <hip/hip_runtime.h>

// 3D trilinear warp (SpatialTransformer), fp32, zeros padding.
// B=2, C=2, D=H=W=160.
//
// Strategy: pre-pack src into staged[b][s] = {c0[s], c1[s], c0[s+1], c1[s+1]}
// so each (dz,dy) corner-pair needs ONE aligned float4 gather (both x-corners,
// both channels) -> 4 scattered loads/site instead of 16.

constexpr int Bv = 2, Cv = 2, Dv = 160, Hv = 160, Wv = 160;
constexpr int V = Dv * Hv * Wv;          // 4,096,000 sites per batch
constexpr int TOTAL = Bv * V;            // 8,192,000
constexpr size_t WS_NEEDED = (size_t)Bv * V * sizeof(float4);  // 131 MB

// ---------------- pack pass (coalesced stream) ----------------
__global__ __launch_bounds__(256) void pack_kernel(
    const float* __restrict__ src,   // [B, C, V]
    float4* __restrict__ staged)     // [B, V]
{
    int i = blockIdx.x * blockDim.x + threadIdx.x;
    if (i >= TOTAL) return;
    int b = i / V;
    int s = i - b * V;
    int x = s % Wv;

    const float* s0 = src + (size_t)b * Cv * V;
    const float* s1 = s0 + V;

    float c00 = s0[s], c10 = s1[s];
    float c01 = 0.f, c11 = 0.f;
    if (x < Wv - 1) { c01 = s0[s + 1]; c11 = s1[s + 1]; }
    staged[i] = make_float4(c00, c10, c01, c11);
}

// ---------------- gather pass ----------------
__global__ __launch_bounds__(256) void warp3d_packed(
    const float4* __restrict__ staged,  // [B, V]
    const float* __restrict__ flow,     // [B, 3, V]
    float* __restrict__ out)            // [B, C, V]
{
    int i = blockIdx.x * blockDim.x + threadIdx.x;
    if (i >= TOTAL) return;

    int b = i / V;
    int s = i - b * V;
    int x = s % Wv;
    int t = s / Wv;
    int y = t % Hv;
    int z = t / Hv;

    const float* fb = flow + (size_t)b * 3 * V;
    float pz = (float)z + fb[s];
    float py = (float)y + fb[s + V];
    float px = (float)x + fb[s + 2 * V];

    float z0f = floorf(pz), y0f = floorf(py), x0f = floorf(px);
    float fz = pz - z0f, fy = py - y0f, fx = px - x0f;
    int z0 = (int)z0f, y0 = (int)y0f, x0 = (int)x0f;

    // x handling: one packed slot covers x0 and x0+1.
    bool vx0 = (unsigned)x0 < (unsigned)Wv;
    bool vx1 = (unsigned)(x0 + 1) < (unsigned)Wv;
    bool lowx = (x0 < 0);                     // clamped-low: slot's first half IS x0+1
    int xc = min(max(x0, 0), Wv - 1);
    float wx0 = vx0 ? (1.f - fx) : 0.f;
    float wx1 = vx1 ? fx : 0.f;

    int zc0 = min(max(z0, 0), Dv - 1);
    int zc1 = min(max(z0 + 1, 0), Dv - 1);
    int yc0 = min(max(y0, 0), Hv - 1);
    int yc1 = min(max(y0 + 1, 0), Hv - 1);
    bool vz0 = (unsigned)z0 < (unsigned)Dv;
    bool vz1 = (unsigned)(z0 + 1) < (unsigned)Dv;
    bool vy0 = (unsigned)y0 < (unsigned)Hv;
    bool vy1 = (unsigned)(y0 + 1) < (unsigned)Hv;
    float wz0 = vz0 ? (1.f - fz) : 0.f;
    float wz1 = vz1 ? fz : 0.f;
    float wy0 = vy0 ? (1.f - fy) : 0.f;
    float wy1 = vy1 ? fy : 0.f;

    int row0 = zc0 * Hv;
    int row1 = zc1 * Hv;
    int idx00 = (row0 + yc0) * Wv + xc;
    int idx01 = (row0 + yc1) * Wv + xc;
    int idx10 = (row1 + yc0) * Wv + xc;
    int idx11 = (row1 + yc1) * Wv + xc;

    const float4* sb = staged + (size_t)b * V;
    float4 q00 = sb[idx00];
    float4 q01 = sb[idx01];
    float4 q10 = sb[idx10];
    float4 q11 = sb[idx11];

    float acc0 = 0.f, acc1 = 0.f;
    {
        float w = wz0 * wy0, a0 = w * wx0, a1 = w * wx1;
        float v1c0 = lowx ? q00.x : q00.z;
        float v1c1 = lowx ? q00.y : q00.w;
        acc0 = fmaf(a0, q00.x, fmaf(a1, v1c0, acc0));
        acc1 = fmaf(a0, q00.y, fmaf(a1, v1c1, acc1));
    }
    {
        float w = wz0 * wy1, a0 = w * wx0, a1 = w * wx1;
        float v1c0 = lowx ? q01.x : q01.z;
        float v1c1 = lowx ? q01.y : q01.w;
        acc0 = fmaf(a0, q01.x, fmaf(a1, v1c0, acc0));
        acc1 = fmaf(a0, q01.y, fmaf(a1, v1c1, acc1));
    }
    {
        float w = wz1 * wy0, a0 = w * wx0, a1 = w * wx1;
        float v1c0 = lowx ? q10.x : q10.z;
        float v1c1 = lowx ? q10.y : q10.w;
        acc0 = fmaf(a0, q10.x, fmaf(a1, v1c0, acc0));
        acc1 = fmaf(a0, q10.y, fmaf(a1, v1c1, acc1));
    }
    {
        float w = wz1 * wy1, a0 = w * wx0, a1 = w * wx1;
        float v1c0 = lowx ? q11.x : q11.z;
        float v1c1 = lowx ? q11.y : q11.w;
        acc0 = fmaf(a0, q11.x, fmaf(a1, v1c0, acc0));
        acc1 = fmaf(a0, q11.y, fmaf(a1, v1c1, acc1));
    }

    size_t ob = (size_t)b * Cv * V;
    out[ob + s]     = acc0;
    out[ob + V + s] = acc1;
}

// ---------------- fallback (no workspace): direct gather ----------------
__global__ __launch_bounds__(256) void warp3d_direct(
    const float* __restrict__ src,
    const float* __restrict__ flow,
    float* __restrict__ out)
{
    int i = blockIdx.x * blockDim.x + threadIdx.x;
    if (i >= TOTAL) return;

    int b = i / V;
    int s = i - b * V;
    int x = s % Wv;
    int t = s / Wv;
    int y = t % Hv;
    int z = t / Hv;

    const float* fb = flow + (size_t)b * 3 * V;
    float pz = (float)z + fb[s];
    float py = (float)y + fb[s + V];
    float px = (float)x + fb[s + 2 * V];

    float z0f = floorf(pz), y0f = floorf(py), x0f = floorf(px);
    float fz = pz - z0f, fy = py - y0f, fx = px - x0f;
    int z0 = (int)z0f, y0 = (int)y0f, x0 = (int)x0f;

    const float* s0 = src + (size_t)b * Cv * V;
    const float* s1 = s0 + V;

    float acc0 = 0.f, acc1 = 0.f;
    #pragma unroll
    for (int dz = 0; dz < 2; ++dz) {
        int zi = z0 + dz;
        bool vz = (unsigned)zi < (unsigned)Dv;
        float wz = dz ? fz : (1.0f - fz);
        #pragma unroll
        for (int dy = 0; dy < 2; ++dy) {
            int yi = y0 + dy;
            bool vy = (unsigned)yi < (unsigned)Hv;
            float wy = dy ? fy : (1.0f - fy);
            #pragma unroll
            for (int dx = 0; dx < 2; ++dx) {
                int xi = x0 + dx;
                bool vx = (unsigned)xi < (unsigned)Wv;
                float wx = dx ? fx : (1.0f - fx);
                if (vz & vy & vx) {
                    int idx = (zi * Hv + yi) * Wv + xi;
                    float w = wz * wy * wx;
                    acc0 = fmaf(w, s0[idx], acc0);
                    acc1 = fmaf(w, s1[idx], acc1);
                }
            }
        }
    }

    size_t ob = (size_t)b * Cv * V;
    out[ob + s]     = acc0;
    out[ob + V + s] = acc1;
}

extern "C" void kernel_launch(void* const* d_in, const int* in_sizes, int n_in,
                              void* d_out, int out_size, void* d_ws, size_t ws_size,
                              hipStream_t stream) {
    const float* src  = (const float*)d_in[0];
    const float* flow = (const float*)d_in[1];
    float* out = (float*)d_out;

    int block = 256;
    int grid = (TOTAL + block - 1) / block;   // 32000 blocks

    if (ws_size >= WS_NEEDED && d_ws != nullptr) {
        float4* staged = (float4*)d_ws;
        pack_kernel<<<grid, block, 0, stream>>>(src, staged);
        warp3d_packed<<<grid, block, 0, stream>>>(staged, flow, out);
    } else {
        warp3d_direct<<<grid, block, 0, stream>>>(src, flow, out);
    }
}

// Round 7
// 378.175 us; speedup vs baseline: 1.5546x; 1.0095x over previous
//
#include <hip/hip_runtime.h>

// 3D trilinear warp (SpatialTransformer), fp32, zeros padding.
// B=2, C=2, D=H=W=160.
//
// Pass 1: pack src into staged[b][s] = {c0[s], c1[s], c0[s+1], c1[s+1]}
//         (vectorized: 4 sites/thread, aligned float4 loads/stores).
// Pass 2: gather with ONE aligned float4 load per (dz,dy) corner-pair
//         (4 scattered 16B loads/site), blocks tiled 32x4y2z with
//         XCD-chunked swizzle so each XCD works a contiguous z-range
//         (staged-slab reuse stays in its 4 MiB L2).

constexpr int Bv = 2, Cv = 2, Dv = 160, Hv = 160, Wv = 160;
constexpr int V = Dv * Hv * Wv;          // 4,096,000 sites per batch
constexpr int TOTAL = Bv * V;            // 8,192,000
constexpr size_t WS_NEEDED = (size_t)Bv * V * sizeof(float4);  // 131 MB

// Tile geometry for the gather pass.
constexpr int TX = 32, TY = 4, TZ = 2;                  // 256 sites/block
constexpr int NTX = Wv / TX;                            // 5
constexpr int NTY = Hv / TY;                            // 40
constexpr int NTZ = Dv / TZ;                            // 80
constexpr int TILES_PER_B = NTX * NTY * NTZ;            // 16000
constexpr int NWG = Bv * TILES_PER_B;                   // 32000
constexpr int NXCD = 8;
constexpr int CHUNK = NWG / NXCD;                       // 4000 (exact)

// ---------------- pack pass (vectorized coalesced stream) ----------------
__global__ __launch_bounds__(256) void pack_kernel4(
    const float* __restrict__ src,   // [B, C, V]
    float4* __restrict__ staged)     // [B, V]
{
    int i = blockIdx.x * blockDim.x + threadIdx.x;   // 0 .. TOTAL/4
    if (i >= TOTAL / 4) return;
    int b = i / (V / 4);
    int s4 = (i - b * (V / 4)) * 4;                  // site base, multiple of 4
    int x = s4 % Wv;                                 // multiple of 4 (W%4==0)

    const float* s0 = src + (size_t)b * Cv * V;
    const float* s1 = s0 + V;

    float4 a0 = *(const float4*)(s0 + s4);
    float4 a1 = *(const float4*)(s1 + s4);
    bool last = (x + 4 >= Wv);                       // row end: x+1 of x=W-1 is invalid
    float b0 = last ? 0.f : s0[s4 + 4];
    float b1 = last ? 0.f : s1[s4 + 4];

    float4* o = staged + (size_t)b * V + s4;
    o[0] = make_float4(a0.x, a1.x, a0.y, a1.y);
    o[1] = make_float4(a0.y, a1.y, a0.z, a1.z);
    o[2] = make_float4(a0.z, a1.z, a0.w, a1.w);
    o[3] = make_float4(a0.w, a1.w, b0, b1);
}

// ---------------- gather pass (3D-tiled, XCD-chunked) ----------------
__global__ __launch_bounds__(256) void warp3d_packed(
    const float4* __restrict__ staged,  // [B, V]
    const float* __restrict__ flow,     // [B, 3, V]
    float* __restrict__ out)            // [B, C, V]
{
    // XCD-chunked bijective swizzle: XCD k gets tiles [k*CHUNK, (k+1)*CHUNK)
    int bid = blockIdx.x;
    int bt = (bid & (NXCD - 1)) * CHUNK + (bid >> 3);

    int b = bt / TILES_PER_B;
    int r = bt - b * TILES_PER_B;              // tile order: x fastest, then y, z
    int tix = r % NTX;
    int t2 = r / NTX;
    int tiy = t2 % NTY;
    int tiz = t2 / NTY;

    int tid = threadIdx.x;
    int x = tix * TX + (tid & (TX - 1));
    int y = tiy * TY + ((tid >> 5) & (TY - 1));
    int z = tiz * TZ + (tid >> 7);
    int s = (z * Hv + y) * Wv + x;

    const float* fb = flow + (size_t)b * 3 * V;
    float pz = (float)z + fb[s];
    float py = (float)y + fb[s + V];
    float px = (float)x + fb[s + 2 * V];

    float z0f = floorf(pz), y0f = floorf(py), x0f = floorf(px);
    float fz = pz - z0f, fy = py - y0f, fx = px - x0f;
    int z0 = (int)z0f, y0 = (int)y0f, x0 = (int)x0f;

    // x handling: one packed slot covers x0 and x0+1.
    bool vx0 = (unsigned)x0 < (unsigned)Wv;
    bool vx1 = (unsigned)(x0 + 1) < (unsigned)Wv;
    bool lowx = (x0 < 0);                     // clamped-low: slot's first half IS x0+1
    int xc = min(max(x0, 0), Wv - 1);
    float wx0 = vx0 ? (1.f - fx) : 0.f;
    float wx1 = vx1 ? fx : 0.f;

    int zc0 = min(max(z0, 0), Dv - 1);
    int zc1 = min(max(z0 + 1, 0), Dv - 1);
    int yc0 = min(max(y0, 0), Hv - 1);
    int yc1 = min(max(y0 + 1, 0), Hv - 1);
    bool vz0 = (unsigned)z0 < (unsigned)Dv;
    bool vz1 = (unsigned)(z0 + 1) < (unsigned)Dv;
    bool vy0 = (unsigned)y0 < (unsigned)Hv;
    bool vy1 = (unsigned)(y0 + 1) < (unsigned)Hv;
    float wz0 = vz0 ? (1.f - fz) : 0.f;
    float wz1 = vz1 ? fz : 0.f;
    float wy0 = vy0 ? (1.f - fy) : 0.f;
    float wy1 = vy1 ? fy : 0.f;

    int row0 = zc0 * Hv;
    int row1 = zc1 * Hv;
    int idx00 = (row0 + yc0) * Wv + xc;
    int idx01 = (row0 + yc1) * Wv + xc;
    int idx10 = (row1 + yc0) * Wv + xc;
    int idx11 = (row1 + yc1) * Wv + xc;

    const float4* sb = staged + (size_t)b * V;
    float4 q00 = sb[idx00];
    float4 q01 = sb[idx01];
    float4 q10 = sb[idx10];
    float4 q11 = sb[idx11];

    float acc0 = 0.f, acc1 = 0.f;
    {
        float w = wz0 * wy0, a0 = w * wx0, a1 = w * wx1;
        float v1c0 = lowx ? q00.x : q00.z;
        float v1c1 = lowx ? q00.y : q00.w;
        acc0 = fmaf(a0, q00.x, fmaf(a1, v1c0, acc0));
        acc1 = fmaf(a0, q00.y, fmaf(a1, v1c1, acc1));
    }
    {
        float w = wz0 * wy1, a0 = w * wx0, a1 = w * wx1;
        float v1c0 = lowx ? q01.x : q01.z;
        float v1c1 = lowx ? q01.y : q01.w;
        acc0 = fmaf(a0, q01.x, fmaf(a1, v1c0, acc0));
        acc1 = fmaf(a0, q01.y, fmaf(a1, v1c1, acc1));
    }
    {
        float w = wz1 * wy0, a0 = w * wx0, a1 = w * wx1;
        float v1c0 = lowx ? q10.x : q10.z;
        float v1c1 = lowx ? q10.y : q10.w;
        acc0 = fmaf(a0, q10.x, fmaf(a1, v1c0, acc0));
        acc1 = fmaf(a0, q10.y, fmaf(a1, v1c1, acc1));
    }
    {
        float w = wz1 * wy1, a0 = w * wx0, a1 = w * wx1;
        float v1c0 = lowx ? q11.x : q11.z;
        float v1c1 = lowx ? q11.y : q11.w;
        acc0 = fmaf(a0, q11.x, fmaf(a1, v1c0, acc0));
        acc1 = fmaf(a0, q11.y, fmaf(a1, v1c1, acc1));
    }

    size_t ob = (size_t)b * Cv * V;
    out[ob + s]     = acc0;
    out[ob + V + s] = acc1;
}

// ---------------- fallback (no workspace): direct gather ----------------
__global__ __launch_bounds__(256) void warp3d_direct(
    const float* __restrict__ src,
    const float* __restrict__ flow,
    float* __restrict__ out)
{
    int i = blockIdx.x * blockDim.x + threadIdx.x;
    if (i >= TOTAL) return;

    int b = i / V;
    int s = i - b * V;
    int x = s % Wv;
    int t = s / Wv;
    int y = t % Hv;
    int z = t / Hv;

    const float* fb = flow + (size_t)b * 3 * V;
    float pz = (float)z + fb[s];
    float py = (float)y + fb[s + V];
    float px = (float)x + fb[s + 2 * V];

    float z0f = floorf(pz), y0f = floorf(py), x0f = floorf(px);
    float fz = pz - z0f, fy = py - y0f, fx = px - x0f;
    int z0 = (int)z0f, y0 = (int)y0f, x0 = (int)x0f;

    const float* s0 = src + (size_t)b * Cv * V;
    const float* s1 = s0 + V;

    float acc0 = 0.f, acc1 = 0.f;
    #pragma unroll
    for (int dz = 0; dz < 2; ++dz) {
        int zi = z0 + dz;
        bool vz = (unsigned)zi < (unsigned)Dv;
        float wz = dz ? fz : (1.0f - fz);
        #pragma unroll
        for (int dy = 0; dy < 2; ++dy) {
            int yi = y0 + dy;
            bool vy = (unsigned)yi < (unsigned)Hv;
            float wy = dy ? fy : (1.0f - fy);
            #pragma unroll
            for (int dx = 0; dx < 2; ++dx) {
                int xi = x0 + dx;
                bool vx = (unsigned)xi < (unsigned)Wv;
                float wx = dx ? fx : (1.0f - fx);
                if (vz & vy & vx) {
                    int idx = (zi * Hv + yi) * Wv + xi;
                    float w = wz * wy * wx;
                    acc0 = fmaf(w, s0[idx], acc0);
                    acc1 = fmaf(w, s1[idx], acc1);
                }
            }
        }
    }

    size_t ob = (size_t)b * Cv * V;
    out[ob + s]     = acc0;
    out[ob + V + s] = acc1;
}

extern "C" void kernel_launch(void* const* d_in, const int* in_sizes, int n_in,
                              void* d_out, int out_size, void* d_ws, size_t ws_size,
                              hipStream_t stream) {
    const float* src  = (const float*)d_in[0];
    const float* flow = (const float*)d_in[1];
    float* out = (float*)d_out;

    if (ws_size >= WS_NEEDED && d_ws != nullptr) {
        float4* staged = (float4*)d_ws;
        int packThreads = TOTAL / 4;
        pack_kernel4<<<(packThreads + 255) / 256, 256, 0, stream>>>(src, staged);
        warp3d_packed<<<NWG, 256, 0, stream>>>(staged, flow, out);
    } else {
        int grid = (TOTAL + 255) / 256;
        warp3d_direct<<<grid, 256, 0, stream>>>(src, flow, out);
    }
}

// Round 8
// 342.309 us; speedup vs baseline: 1.7175x; 1.1048x over previous
//
#include <hip/hip_runtime.h>

// 3D trilinear warp (SpatialTransformer), fp32, zeros padding.
// B=2, C=2, D=H=W=160.
//
// Pass 1: pack src into staged[b][s] = {c0[s], c1[s], c0[s+1], c1[s+1]}
//         (1 site/thread: scalar loads, ONE coalesced float4 store — the
//         4-site variant's strided stores measured slower).
// Pass 2: gather, 4 x-consecutive sites PER THREAD for memory-level
//         parallelism: 3 float4 flow loads -> 16 independent float4
//         gathers in flight -> 2 float4 stores. Tiles (32x,8y,4z),
//         XCD-chunked swizzle for per-XCD L2 locality on staged.

constexpr int Bv = 2, Cv = 2, Dv = 160, Hv = 160, Wv = 160;
constexpr int V = Dv * Hv * Wv;          // 4,096,000 sites per batch
constexpr int TOTAL = Bv * V;            // 8,192,000
constexpr size_t WS_NEEDED = (size_t)Bv * V * sizeof(float4);  // 131 MB

// Gather tile geometry: 1024 sites/block, 256 threads, 4 sites/thread.
constexpr int TX = 32, TY = 8, TZ = 4;                  // sites per tile
constexpr int NTX = Wv / TX;                            // 5
constexpr int NTY = Hv / TY;                            // 20
constexpr int NTZ = Dv / TZ;                            // 40
constexpr int TILES_PER_B = NTX * NTY * NTZ;            // 4000
constexpr int NWG = Bv * TILES_PER_B;                   // 8000
constexpr int NXCD = 8;
constexpr int CHUNK = NWG / NXCD;                       // 1000 (exact)

// ---------------- pack pass (coalesced stream, 1 site/thread) ----------------
__global__ __launch_bounds__(256) void pack_kernel(
    const float* __restrict__ src,   // [B, C, V]
    float4* __restrict__ staged)     // [B, V]
{
    int i = blockIdx.x * blockDim.x + threadIdx.x;
    if (i >= TOTAL) return;
    int b = i / V;
    int s = i - b * V;
    int x = s % Wv;

    const float* s0 = src + (size_t)b * Cv * V;
    const float* s1 = s0 + V;

    float c00 = s0[s], c10 = s1[s];
    float c01 = 0.f, c11 = 0.f;
    if (x < Wv - 1) { c01 = s0[s + 1]; c11 = s1[s + 1]; }
    staged[i] = make_float4(c00, c10, c01, c11);
}

// ---------------- gather pass (4 sites/thread, 3D-tiled, XCD-chunked) -------
__global__ __launch_bounds__(256) void warp3d_packed4(
    const float4* __restrict__ staged,  // [B, V]
    const float* __restrict__ flow,     // [B, 3, V]
    float* __restrict__ out)            // [B, C, V]
{
    // XCD-chunked bijective swizzle (NWG % 8 == 0).
    int bid = blockIdx.x;
    int bt = (bid & (NXCD - 1)) * CHUNK + (bid >> 3);

    int b = bt / TILES_PER_B;
    int r = bt - b * TILES_PER_B;              // tile order: x fastest, then y, z
    int tix = r % NTX;
    int t2 = r / NTX;
    int tiy = t2 % NTY;
    int tiz = t2 / NTY;

    int tid = threadIdx.x;
    int x = tix * TX + (tid & 7) * 4;          // x-quad base (aligned to 4)
    int y = tiy * TY + ((tid >> 3) & 7);
    int z = tiz * TZ + (tid >> 6);
    int s = (z * Hv + y) * Wv + x;             // multiple of 4

    const float* fb = flow + (size_t)b * 3 * V;
    float4 fzv = *(const float4*)(fb + s);
    float4 fyv = *(const float4*)(fb + s + V);
    float4 fxv = *(const float4*)(fb + s + 2 * V);
    float fzk[4] = {fzv.x, fzv.y, fzv.z, fzv.w};
    float fyk[4] = {fyv.x, fyv.y, fyv.z, fyv.w};
    float fxk[4] = {fxv.x, fxv.y, fxv.z, fxv.w};

    // Per-site weights / indices (all static indexing).
    float wz0[4], wz1[4], wy0[4], wy1[4], wx0[4], wx1[4];
    bool lowx[4];
    int idx[4][4];

    #pragma unroll
    for (int k = 0; k < 4; ++k) {
        float pz = (float)z + fzk[k];
        float py = (float)y + fyk[k];
        float px = (float)(x + k) + fxk[k];

        float z0f = floorf(pz), y0f = floorf(py), x0f = floorf(px);
        float fz = pz - z0f, fy = py - y0f, fx = px - x0f;
        int z0 = (int)z0f, y0 = (int)y0f, x0 = (int)x0f;

        bool vx0 = (unsigned)x0 < (unsigned)Wv;
        bool vx1 = (unsigned)(x0 + 1) < (unsigned)Wv;
        lowx[k] = (x0 < 0);
        int xc = min(max(x0, 0), Wv - 1);
        wx0[k] = vx0 ? (1.f - fx) : 0.f;
        wx1[k] = vx1 ? fx : 0.f;

        int zc0 = min(max(z0, 0), Dv - 1);
        int zc1 = min(max(z0 + 1, 0), Dv - 1);
        int yc0 = min(max(y0, 0), Hv - 1);
        int yc1 = min(max(y0 + 1, 0), Hv - 1);
        wz0[k] = ((unsigned)z0 < (unsigned)Dv) ? (1.f - fz) : 0.f;
        wz1[k] = ((unsigned)(z0 + 1) < (unsigned)Dv) ? fz : 0.f;
        wy0[k] = ((unsigned)y0 < (unsigned)Hv) ? (1.f - fy) : 0.f;
        wy1[k] = ((unsigned)(y0 + 1) < (unsigned)Hv) ? fy : 0.f;

        idx[k][0] = (zc0 * Hv + yc0) * Wv + xc;
        idx[k][1] = (zc0 * Hv + yc1) * Wv + xc;
        idx[k][2] = (zc1 * Hv + yc0) * Wv + xc;
        idx[k][3] = (zc1 * Hv + yc1) * Wv + xc;
    }

    // Issue all 16 gathers back-to-back (MLP).
    const float4* sb = staged + (size_t)b * V;
    float4 q[4][4];
    #pragma unroll
    for (int k = 0; k < 4; ++k) {
        #pragma unroll
        for (int j = 0; j < 4; ++j) {
            q[k][j] = sb[idx[k][j]];
        }
    }

    float acc0[4], acc1[4];
    #pragma unroll
    for (int k = 0; k < 4; ++k) {
        float wzy[4] = {wz0[k] * wy0[k], wz0[k] * wy1[k],
                        wz1[k] * wy0[k], wz1[k] * wy1[k]};
        float a0 = 0.f, a1 = 0.f;
        #pragma unroll
        for (int j = 0; j < 4; ++j) {
            float c0lo = q[k][j].x, c1lo = q[k][j].y;
            float c0hi = lowx[k] ? q[k][j].x : q[k][j].z;
            float c1hi = lowx[k] ? q[k][j].y : q[k][j].w;
            float b0 = wzy[j] * wx0[k], b1 = wzy[j] * wx1[k];
            a0 = fmaf(b0, c0lo, fmaf(b1, c0hi, a0));
            a1 = fmaf(b0, c1lo, fmaf(b1, c1hi, a1));
        }
        acc0[k] = a0;
        acc1[k] = a1;
    }

    size_t ob = (size_t)b * Cv * V;
    *(float4*)(out + ob + s)     = make_float4(acc0[0], acc0[1], acc0[2], acc0[3]);
    *(float4*)(out + ob + V + s) = make_float4(acc1[0], acc1[1], acc1[2], acc1[3]);
}

// ---------------- fallback (no workspace): direct gather ----------------
__global__ __launch_bounds__(256) void warp3d_direct(
    const float* __restrict__ src,
    const float* __restrict__ flow,
    float* __restrict__ out)
{
    int i = blockIdx.x * blockDim.x + threadIdx.x;
    if (i >= TOTAL) return;

    int b = i / V;
    int s = i - b * V;
    int x = s % Wv;
    int t = s / Wv;
    int y = t % Hv;
    int z = t / Hv;

    const float* fb = flow + (size_t)b * 3 * V;
    float pz = (float)z + fb[s];
    float py = (float)y + fb[s + V];
    float px = (float)x + fb[s + 2 * V];

    float z0f = floorf(pz), y0f = floorf(py), x0f = floorf(px);
    float fz = pz - z0f, fy = py - y0f, fx = px - x0f;
    int z0 = (int)z0f, y0 = (int)y0f, x0 = (int)x0f;

    const float* s0 = src + (size_t)b * Cv * V;
    const float* s1 = s0 + V;

    float acc0 = 0.f, acc1 = 0.f;
    #pragma unroll
    for (int dz = 0; dz < 2; ++dz) {
        int zi = z0 + dz;
        bool vz = (unsigned)zi < (unsigned)Dv;
        float wz = dz ? fz : (1.0f - fz);
        #pragma unroll
        for (int dy = 0; dy < 2; ++dy) {
            int yi = y0 + dy;
            bool vy = (unsigned)yi < (unsigned)Hv;
            float wy = dy ? fy : (1.0f - fy);
            #pragma unroll
            for (int dx = 0; dx < 2; ++dx) {
                int xi = x0 + dx;
                bool vx = (unsigned)xi < (unsigned)Wv;
                float wx = dx ? fx : (1.0f - fx);
                if (vz & vy & vx) {
                    int idx = (zi * Hv + yi) * Wv + xi;
                    float w = wz * wy * wx;
                    acc0 = fmaf(w, s0[idx], acc0);
                    acc1 = fmaf(w, s1[idx], acc1);
                }
            }
        }
    }

    size_t ob = (size_t)b * Cv * V;
    out[ob + s]     = acc0;
    out[ob + V + s] = acc1;
}

extern "C" void kernel_launch(void* const* d_in, const int* in_sizes, int n_in,
                              void* d_out, int out_size, void* d_ws, size_t ws_size,
                              hipStream_t stream) {
    const float* src  = (const float*)d_in[0];
    const float* flow = (const float*)d_in[1];
    float* out = (float*)d_out;

    if (ws_size >= WS_NEEDED && d_ws != nullptr) {
        float4* staged = (float4*)d_ws;
        pack_kernel<<<(TOTAL + 255) / 256, 256, 0, stream>>>(src, staged);
        warp3d_packed4<<<NWG, 256, 0, stream>>>(staged, flow, out);
    } else {
        int grid = (TOTAL + 255) / 256;
        warp3d_direct<<<grid, 256, 0, stream>>>(src, flow, out);
    }
}

// Round 9
// 340.744 us; speedup vs baseline: 1.7254x; 1.0046x over previous
//
#include <hip/hip_runtime.h>

// 3D trilinear warp (SpatialTransformer), fp32, zeros padding.
// B=2, C=2, D=H=W=160.
//
// Pass 1: pack src into staged[b][s] = {c0[s], c1[s], c0[s+1], c1[s+1]}
//         (1 site/thread, coalesced float4 store; ~45us, near stream floor).
// Pass 2: gather, 4 x-consecutive sites PER THREAD; 16 float4 gathers
//         issued back-to-back. __launch_bounds__(256,4) raises the VGPR
//         cap to 128 so all 16 stay in flight (R8's 64-VGPR allocation
//         serialized them to ~6). Tiles (32x,8y,4z), XCD-chunked swizzle.

constexpr int Bv = 2, Cv = 2, Dv = 160, Hv = 160, Wv = 160;
constexpr int V = Dv * Hv * Wv;          // 4,096,000 sites per batch
constexpr int TOTAL = Bv * V;            // 8,192,000
constexpr size_t WS_NEEDED = (size_t)Bv * V * sizeof(float4);  // 131 MB

// Gather tile geometry: 1024 sites/block, 256 threads, 4 sites/thread.
constexpr int TX = 32, TY = 8, TZ = 4;                  // sites per tile
constexpr int NTX = Wv / TX;                            // 5
constexpr int NTY = Hv / TY;                            // 20
constexpr int NTZ = Dv / TZ;                            // 40
constexpr int TILES_PER_B = NTX * NTY * NTZ;            // 4000
constexpr int NWG = Bv * TILES_PER_B;                   // 8000
constexpr int NXCD = 8;
constexpr int CHUNK = NWG / NXCD;                       // 1000 (exact)

// ---------------- pack pass (coalesced stream, 1 site/thread) ----------------
__global__ __launch_bounds__(256) void pack_kernel(
    const float* __restrict__ src,   // [B, C, V]
    float4* __restrict__ staged)     // [B, V]
{
    int i = blockIdx.x * blockDim.x + threadIdx.x;
    if (i >= TOTAL) return;
    int b = i / V;
    int s = i - b * V;
    int x = s % Wv;

    const float* s0 = src + (size_t)b * Cv * V;
    const float* s1 = s0 + V;

    float c00 = s0[s], c10 = s1[s];
    float c01 = 0.f, c11 = 0.f;
    if (x < Wv - 1) { c01 = s0[s + 1]; c11 = s1[s + 1]; }
    staged[i] = make_float4(c00, c10, c01, c11);
}

// ---------------- gather pass (4 sites/thread, 3D-tiled, XCD-chunked) -------
__global__ __launch_bounds__(256, 4) void warp3d_packed4(
    const float4* __restrict__ staged,  // [B, V]
    const float* __restrict__ flow,     // [B, 3, V]
    float* __restrict__ out)            // [B, C, V]
{
    // XCD-chunked bijective swizzle (NWG % 8 == 0).
    int bid = blockIdx.x;
    int bt = (bid & (NXCD - 1)) * CHUNK + (bid >> 3);

    int b = bt / TILES_PER_B;
    int r = bt - b * TILES_PER_B;              // tile order: x fastest, then y, z
    int tix = r % NTX;
    int t2 = r / NTX;
    int tiy = t2 % NTY;
    int tiz = t2 / NTY;

    int tid = threadIdx.x;
    int x = tix * TX + (tid & 7) * 4;          // x-quad base (aligned to 4)
    int y = tiy * TY + ((tid >> 3) & 7);
    int z = tiz * TZ + (tid >> 6);
    int s = (z * Hv + y) * Wv + x;             // multiple of 4

    const float* fb = flow + (size_t)b * 3 * V;
    float4 fzv = *(const float4*)(fb + s);
    float4 fyv = *(const float4*)(fb + s + V);
    float4 fxv = *(const float4*)(fb + s + 2 * V);
    float fzk[4] = {fzv.x, fzv.y, fzv.z, fzv.w};
    float fyk[4] = {fyv.x, fyv.y, fyv.z, fyv.w};
    float fxk[4] = {fxv.x, fxv.y, fxv.z, fxv.w};

    // Per-site weights / indices (all static indexing).
    float wz0[4], wz1[4], wy0[4], wy1[4], wx0[4], wx1[4];
    bool lowx[4];
    int idx[4][4];

    #pragma unroll
    for (int k = 0; k < 4; ++k) {
        float pz = (float)z + fzk[k];
        float py = (float)y + fyk[k];
        float px = (float)(x + k) + fxk[k];

        float z0f = floorf(pz), y0f = floorf(py), x0f = floorf(px);
        float fz = pz - z0f, fy = py - y0f, fx = px - x0f;
        int z0 = (int)z0f, y0 = (int)y0f, x0 = (int)x0f;

        bool vx0 = (unsigned)x0 < (unsigned)Wv;
        bool vx1 = (unsigned)(x0 + 1) < (unsigned)Wv;
        lowx[k] = (x0 < 0);
        int xc = min(max(x0, 0), Wv - 1);
        wx0[k] = vx0 ? (1.f - fx) : 0.f;
        wx1[k] = vx1 ? fx : 0.f;

        int zc0 = min(max(z0, 0), Dv - 1);
        int zc1 = min(max(z0 + 1, 0), Dv - 1);
        int yc0 = min(max(y0, 0), Hv - 1);
        int yc1 = min(max(y0 + 1, 0), Hv - 1);
        wz0[k] = ((unsigned)z0 < (unsigned)Dv) ? (1.f - fz) : 0.f;
        wz1[k] = ((unsigned)(z0 + 1) < (unsigned)Dv) ? fz : 0.f;
        wy0[k] = ((unsigned)y0 < (unsigned)Hv) ? (1.f - fy) : 0.f;
        wy1[k] = ((unsigned)(y0 + 1) < (unsigned)Hv) ? fy : 0.f;

        idx[k][0] = (zc0 * Hv + yc0) * Wv + xc;
        idx[k][1] = (zc0 * Hv + yc1) * Wv + xc;
        idx[k][2] = (zc1 * Hv + yc0) * Wv + xc;
        idx[k][3] = (zc1 * Hv + yc1) * Wv + xc;
    }

    // Issue all 16 gathers back-to-back (MLP) — 128-VGPR budget holds them.
    const float4* sb = staged + (size_t)b * V;
    float4 q[4][4];
    #pragma unroll
    for (int k = 0; k < 4; ++k) {
        #pragma unroll
        for (int j = 0; j < 4; ++j) {
            q[k][j] = sb[idx[k][j]];
        }
    }

    float acc0[4], acc1[4];
    #pragma unroll
    for (int k = 0; k < 4; ++k) {
        float wzy[4] = {wz0[k] * wy0[k], wz0[k] * wy1[k],
                        wz1[k] * wy0[k], wz1[k] * wy1[k]};
        float a0 = 0.f, a1 = 0.f;
        #pragma unroll
        for (int j = 0; j < 4; ++j) {
            float c0lo = q[k][j].x, c1lo = q[k][j].y;
            float c0hi = lowx[k] ? q[k][j].x : q[k][j].z;
            float c1hi = lowx[k] ? q[k][j].y : q[k][j].w;
            float b0 = wzy[j] * wx0[k], b1 = wzy[j] * wx1[k];
            a0 = fmaf(b0, c0lo, fmaf(b1, c0hi, a0));
            a1 = fmaf(b0, c1lo, fmaf(b1, c1hi, a1));
        }
        acc0[k] = a0;
        acc1[k] = a1;
    }

    size_t ob = (size_t)b * Cv * V;
    *(float4*)(out + ob + s)     = make_float4(acc0[0], acc0[1], acc0[2], acc0[3]);
    *(float4*)(out + ob + V + s) = make_float4(acc1[0], acc1[1], acc1[2], acc1[3]);
}

// ---------------- fallback (no workspace): direct gather ----------------
__global__ __launch_bounds__(256) void warp3d_direct(
    const float* __restrict__ src,
    const float* __restrict__ flow,
    float* __restrict__ out)
{
    int i = blockIdx.x * blockDim.x + threadIdx.x;
    if (i >= TOTAL) return;

    int b = i / V;
    int s = i - b * V;
    int x = s % Wv;
    int t = s / Wv;
    int y = t % Hv;
    int z = t / Hv;

    const float* fb = flow + (size_t)b * 3 * V;
    float pz = (float)z + fb[s];
    float py = (float)y + fb[s + V];
    float px = (float)x + fb[s + 2 * V];

    float z0f = floorf(pz), y0f = floorf(py), x0f = floorf(px);
    float fz = pz - z0f, fy = py - y0f, fx = px - x0f;
    int z0 = (int)z0f, y0 = (int)y0f, x0 = (int)x0f;

    const float* s0 = src + (size_t)b * Cv * V;
    const float* s1 = s0 + V;

    float acc0 = 0.f, acc1 = 0.f;
    #pragma unroll
    for (int dz = 0; dz < 2; ++dz) {
        int zi = z0 + dz;
        bool vz = (unsigned)zi < (unsigned)Dv;
        float wz = dz ? fz : (1.0f - fz);
        #pragma unroll
        for (int dy = 0; dy < 2; ++dy) {
            int yi = y0 + dy;
            bool vy = (unsigned)yi < (unsigned)Hv;
            float wy = dy ? fy : (1.0f - fy);
            #pragma unroll
            for (int dx = 0; dx < 2; ++dx) {
                int xi = x0 + dx;
                bool vx = (unsigned)xi < (unsigned)Wv;
                float wx = dx ? fx : (1.0f - fx);
                if (vz & vy & vx) {
                    int idx = (zi * Hv + yi) * Wv + xi;
                    float w = wz * wy * wx;
                    acc0 = fmaf(w, s0[idx], acc0);
                    acc1 = fmaf(w, s1[idx], acc1);
                }
            }
        }
    }

    size_t ob = (size_t)b * Cv * V;
    out[ob + s]     = acc0;
    out[ob + V + s] = acc1;
}

extern "C" void kernel_launch(void* const* d_in, const int* in_sizes, int n_in,
                              void* d_out, int out_size, void* d_ws, size_t ws_size,
                              hipStream_t stream) {
    const float* src  = (const float*)d_in[0];
    const float* flow = (const float*)d_in[1];
    float* out = (float*)d_out;

    if (ws_size >= WS_NEEDED && d_ws != nullptr) {
        float4* staged = (float4*)d_ws;
        pack_kernel<<<(TOTAL + 255) / 256, 256, 0, stream>>>(src, staged);
        warp3d_packed4<<<NWG, 256, 0, stream>>>(staged, flow, out);
    } else {
        int grid = (TOTAL + 255) / 256;
        warp3d_direct<<<grid, 256, 0, stream>>>(src, flow, out);
    }
}

// Round 11
// 324.188 us; speedup vs baseline: 1.8135x; 1.0511x over previous
//
#include <hip/hip_runtime.h>

// 3D trilinear warp (SpatialTransformer), fp32, zeros padding.
// B=2, C=2, D=H=W=160.
//
// Pass 1: pack src into staged[b][s] = {c0[s], c1[s], c0[s+W], c1[s+W]}
//         (y-PAIR packing). A site's 4 gathers are then (z,x) corner
//         combos whose x-pairs sit 16B apart -> same 64B line 75% of the
//         time: distinct lines/site drops 4 -> 2.5 vs x-pair packing.
// Pass 2: gather, 4 x-consecutive sites/thread, plain C++ loads
//         (R10's forced-asm MLP corrupted in-flight loads via spills).
//         Tiles (32x,8y,4z), XCD-chunked swizzle (per-XCD L2 locality).

constexpr int Bv = 2, Cv = 2, Dv = 160, Hv = 160, Wv = 160;
constexpr int V = Dv * Hv * Wv;          // 4,096,000 sites per batch
constexpr int TOTAL = Bv * V;            // 8,192,000
constexpr size_t WS_NEEDED = (size_t)Bv * V * sizeof(float4);  // 131 MB

// Gather tile geometry: 1024 sites/block, 256 threads, 4 sites/thread.
constexpr int TX = 32, TY = 8, TZ = 4;
constexpr int NTX = Wv / TX;                            // 5
constexpr int NTY = Hv / TY;                            // 20
constexpr int NTZ = Dv / TZ;                            // 40
constexpr int TILES_PER_B = NTX * NTY * NTZ;            // 4000
constexpr int NWG = Bv * TILES_PER_B;                   // 8000
constexpr int NXCD = 8;
constexpr int CHUNK = NWG / NXCD;                       // 1000 (exact)

// ---------------- pack pass (y-pair layout, coalesced) ----------------
__global__ __launch_bounds__(256) void pack_kernel_y(
    const float* __restrict__ src,   // [B, C, V]
    float4* __restrict__ staged)     // [B, V]
{
    int i = blockIdx.x * blockDim.x + threadIdx.x;
    if (i >= TOTAL) return;
    int b = i / V;
    int s = i - b * V;
    int y = (s / Wv) % Hv;

    const float* s0 = src + (size_t)b * Cv * V;
    const float* s1 = s0 + V;

    float c00 = s0[s], c10 = s1[s];
    float c01 = 0.f, c11 = 0.f;
    if (y < Hv - 1) { c01 = s0[s + Wv]; c11 = s1[s + Wv]; }
    staged[i] = make_float4(c00, c10, c01, c11);
}

// ---------------- gather pass (4 sites/thread, 3D-tiled, XCD-chunked) -------
__global__ __launch_bounds__(256) void warp3d_packed4(
    const float4* __restrict__ staged,  // [B, V]  (y-pair slots)
    const float* __restrict__ flow,     // [B, 3, V]
    float* __restrict__ out)            // [B, C, V]
{
    // XCD-chunked bijective swizzle (NWG % 8 == 0).
    int bid = blockIdx.x;
    int bt = (bid & (NXCD - 1)) * CHUNK + (bid >> 3);

    int b = bt / TILES_PER_B;
    int r = bt - b * TILES_PER_B;              // tile order: x fastest, then y, z
    int tix = r % NTX;
    int t2 = r / NTX;
    int tiy = t2 % NTY;
    int tiz = t2 / NTY;

    int tid = threadIdx.x;
    int x = tix * TX + (tid & 7) * 4;          // x-quad base (aligned to 4)
    int y = tiy * TY + ((tid >> 3) & 7);
    int z = tiz * TZ + (tid >> 6);
    int s = (z * Hv + y) * Wv + x;             // multiple of 4

    const float* fb = flow + (size_t)b * 3 * V;
    float4 fzv = *(const float4*)(fb + s);
    float4 fyv = *(const float4*)(fb + s + V);
    float4 fxv = *(const float4*)(fb + s + 2 * V);
    float fzk[4] = {fzv.x, fzv.y, fzv.z, fzv.w};
    float fyk[4] = {fyv.x, fyv.y, fyv.z, fyv.w};
    float fxk[4] = {fxv.x, fxv.y, fxv.z, fxv.w};

    // Per-site weights / indices (all static indexing).
    float wz0[4], wz1[4], wy0[4], wy1[4], wx0[4], wx1[4];
    bool lowy[4];
    int idx[4][4];

    #pragma unroll
    for (int k = 0; k < 4; ++k) {
        float pz = (float)z + fzk[k];
        float py = (float)y + fyk[k];
        float px = (float)(x + k) + fxk[k];

        float z0f = floorf(pz), y0f = floorf(py), x0f = floorf(px);
        float fz = pz - z0f, fy = py - y0f, fx = px - x0f;
        int z0 = (int)z0f, y0 = (int)y0f, x0 = (int)x0f;

        // y handling: one slot covers y0 and y0+1.
        lowy[k] = (y0 < 0);                    // clamped-low: slot's first half IS y0+1
        int yc = min(max(y0, 0), Hv - 1);
        wy0[k] = ((unsigned)y0 < (unsigned)Hv) ? (1.f - fy) : 0.f;
        wy1[k] = ((unsigned)(y0 + 1) < (unsigned)Hv) ? fy : 0.f;

        int xc0 = min(max(x0, 0), Wv - 1);
        int xc1 = min(max(x0 + 1, 0), Wv - 1);
        wx0[k] = ((unsigned)x0 < (unsigned)Wv) ? (1.f - fx) : 0.f;
        wx1[k] = ((unsigned)(x0 + 1) < (unsigned)Wv) ? fx : 0.f;

        int zc0 = min(max(z0, 0), Dv - 1);
        int zc1 = min(max(z0 + 1, 0), Dv - 1);
        wz0[k] = ((unsigned)z0 < (unsigned)Dv) ? (1.f - fz) : 0.f;
        wz1[k] = ((unsigned)(z0 + 1) < (unsigned)Dv) ? fz : 0.f;

        int rowz0 = (zc0 * Hv + yc) * Wv;
        int rowz1 = (zc1 * Hv + yc) * Wv;
        idx[k][0] = rowz0 + xc0;   // (z0, x0)   — idx[k][0],[1] share a line 75%
        idx[k][1] = rowz0 + xc1;   // (z0, x0+1)
        idx[k][2] = rowz1 + xc0;   // (z1, x0)
        idx[k][3] = rowz1 + xc1;   // (z1, x0+1)
    }

    const float4* sb = staged + (size_t)b * V;
    float4 q[4][4];
    #pragma unroll
    for (int k = 0; k < 4; ++k) {
        #pragma unroll
        for (int j = 0; j < 4; ++j) {
            q[k][j] = sb[idx[k][j]];
        }
    }

    float acc0[4], acc1[4];
    #pragma unroll
    for (int k = 0; k < 4; ++k) {
        // weight per (z,x) corner pair
        float wzx[4] = {wz0[k] * wx0[k], wz0[k] * wx1[k],
                        wz1[k] * wx0[k], wz1[k] * wx1[k]};
        float a0 = 0.f, a1 = 0.f;
        #pragma unroll
        for (int j = 0; j < 4; ++j) {
            float y0c0 = q[k][j].x, y0c1 = q[k][j].y;
            float y1c0 = lowy[k] ? q[k][j].x : q[k][j].z;
            float y1c1 = lowy[k] ? q[k][j].y : q[k][j].w;
            float b0 = wzx[j] * wy0[k], b1 = wzx[j] * wy1[k];
            a0 = fmaf(b0, y0c0, fmaf(b1, y1c0, a0));
            a1 = fmaf(b0, y0c1, fmaf(b1, y1c1, a1));
        }
        acc0[k] = a0;
        acc1[k] = a1;
    }

    size_t ob = (size_t)b * Cv * V;
    *(float4*)(out + ob + s)     = make_float4(acc0[0], acc0[1], acc0[2], acc0[3]);
    *(float4*)(out + ob + V + s) = make_float4(acc1[0], acc1[1], acc1[2], acc1[3]);
}

// ---------------- fallback (no workspace): direct gather ----------------
__global__ __launch_bounds__(256) void warp3d_direct(
    const float* __restrict__ src,
    const float* __restrict__ flow,
    float* __restrict__ out)
{
    int i = blockIdx.x * blockDim.x + threadIdx.x;
    if (i >= TOTAL) return;

    int b = i / V;
    int s = i - b * V;
    int x = s % Wv;
    int t = s / Wv;
    int y = t % Hv;
    int z = t / Hv;

    const float* fb = flow + (size_t)b * 3 * V;
    float pz = (float)z + fb[s];
    float py = (float)y + fb[s + V];
    float px = (float)x + fb[s + 2 * V];

    float z0f = floorf(pz), y0f = floorf(py), x0f = floorf(px);
    float fz = pz - z0f, fy = py - y0f, fx = px - x0f;
    int z0 = (int)z0f, y0 = (int)y0f, x0 = (int)x0f;

    const float* s0 = src + (size_t)b * Cv * V;
    const float* s1 = s0 + V;

    float acc0 = 0.f, acc1 = 0.f;
    #pragma unroll
    for (int dz = 0; dz < 2; ++dz) {
        int zi = z0 + dz;
        bool vz = (unsigned)zi < (unsigned)Dv;
        float wz = dz ? fz : (1.0f - fz);
        #pragma unroll
        for (int dy = 0; dy < 2; ++dy) {
            int yi = y0 + dy;
            bool vy = (unsigned)yi < (unsigned)Hv;
            float wy = dy ? fy : (1.0f - fy);
            #pragma unroll
            for (int dx = 0; dx < 2; ++dx) {
                int xi = x0 + dx;
                bool vx = (unsigned)xi < (unsigned)Wv;
                float wx = dx ? fx : (1.0f - fx);
                if (vz & vy & vx) {
                    int idx = (zi * Hv + yi) * Wv + xi;
                    float w = wz * wy * wx;
                    acc0 = fmaf(w, s0[idx], acc0);
                    acc1 = fmaf(w, s1[idx], acc1);
                }
            }
        }
    }

    size_t ob = (size_t)b * Cv * V;
    out[ob + s]     = acc0;
    out[ob + V + s] = acc1;
}

extern "C" void kernel_launch(void* const* d_in, const int* in_sizes, int n_in,
                              void* d_out, int out_size, void* d_ws, size_t ws_size,
                              hipStream_t stream) {
    const float* src  = (const float*)d_in[0];
    const float* flow = (const float*)d_in[1];
    float* out = (float*)d_out;

    if (ws_size >= WS_NEEDED && d_ws != nullptr) {
        float4* staged = (float4*)d_ws;
        pack_kernel_y<<<(TOTAL + 255) / 256, 256, 0, stream>>>(src, staged);
        warp3d_packed4<<<NWG, 256, 0, stream>>>(staged, flow, out);
    } else {
        int grid = (TOTAL + 255) / 256;
        warp3d_direct<<<grid, 256, 0, stream>>>(src, flow, out);
    }
}